// Round 4
// baseline (132.984 us; speedup 1.0000x reference)
//
#include <hip/hip_runtime.h>

typedef __bf16 bf16x8 __attribute__((ext_vector_type(8)));
typedef float f32x4 __attribute__((ext_vector_type(4)));

#define C_IN 128
#define HW_IN 3136      // 56*56
#define K_OUT 256
#define OWP 56          // padded output width
#define M_PER_IMG 3024  // 54*56
#define KG 1152         // 128*9
#define OUT_HW 2916     // 54*54
#define BN 192
#define NBLK 504        // 96768 / 192 = 504 = 8*63

// ws layout (bytes):
//   [0,4)          : absmax bits (uint)
//   [4096, 593920) : Bt bf16 [256][1152], kk = (r*3+s)*128 + c
//   [593920, ...)  : xt bf16 [n][h][w][c] + tail pad  (25.69 MB)

static __device__ __forceinline__ unsigned short f2bf(float f) {
  unsigned u = __float_as_uint(f);
  u += 0x7FFFu + ((u >> 16) & 1);   // RNE
  return (unsigned short)(u >> 16);
}

// async global->LDS, 16B per lane; dest = wave-uniform base + lane*16
static __device__ __forceinline__ void gload16(const unsigned short* g, unsigned short* l) {
  __builtin_amdgcn_global_load_lds(
      (const __attribute__((address_space(1))) unsigned int*)g,
      (__attribute__((address_space(3))) unsigned int*)l, 16, 0, 0);
}

__global__ __launch_bounds__(256) void k_absmax(const float* __restrict__ w,
                                                unsigned* __restrict__ mx) {
  __shared__ float red[256];
  const int t = threadIdx.x;
  float v = fabsf(w[blockIdx.x * 256 + t]);
  red[t] = v;
  __syncthreads();
  for (int s = 128; s > 0; s >>= 1) {
    if (t < s) red[t] = fmaxf(red[t], red[t + s]);
    __syncthreads();
  }
  if (t == 0) atomicMax(mx, __float_as_uint(red[0]));
}

__global__ __launch_bounds__(256) void k_quant(const float* __restrict__ w,
                                               const unsigned* __restrict__ mx,
                                               unsigned short* __restrict__ bt) {
  const int idx = blockIdx.x * 256 + threadIdx.x;  // < 294912
  const float thr = 0.05f * __uint_as_float(*mx);
  const int k = idx / KG;
  const int j = idx - k * KG;
  const int rs = j >> 7;      // 0..8
  const int c = j & 127;
  const float v = w[k * KG + c * 9 + rs];
  float q = 0.f;
  if (v > thr) q = 1.f;
  else if (v < -thr) q = -1.f;
  bt[idx] = f2bf(q);
}

// x fp32 NCHW -> xt bf16 [n][hw][c], LDS tile transpose, XOR-swizzled (c^j)
__global__ __launch_bounds__(256) void k_xt(const float* __restrict__ x,
                                            unsigned short* __restrict__ xt) {
  __shared__ unsigned short tile[8192];  // [j:64][c:128], phys c = c ^ j
  const int n = blockIdx.x / 49;
  const int hw0 = (blockIdx.x - n * 49) * 64;
  const int t = threadIdx.x;
  const int j = t & 63;
  const int ci = t >> 6;
  const float* xp = x + (size_t)n * (C_IN * HW_IN) + hw0 + j;
#pragma unroll
  for (int it = 0; it < 32; ++it) {
    const int c = it * 4 + ci;
    tile[j * 128 + (c ^ j)] = f2bf(xp[(size_t)c * HW_IN]);
  }
  __syncthreads();
  const int jj = t >> 2;
  const int q = t & 3;
  unsigned short v[32] __attribute__((aligned(16)));
#pragma unroll
  for (int i = 0; i < 32; ++i)
    v[i] = tile[jj * 128 + ((q * 32 + i) ^ jj)];
  uint4* dst = (uint4*)(xt + (size_t)(n * HW_IN + hw0 + jj) * 128 + q * 32);
#pragma unroll
  for (int u = 0; u < 4; ++u)
    dst[u] = *(const uint4*)&v[u * 8];
}

// GEMM: D[kch][m] = sum_kk Bt[kch][kk] * A[m][kk]
// Tile 256 kch x 192 spatial, BK=64, 8 waves (2M x 4N), 512 threads.
// 8-phase-style schedule: STAGE(t+1) issued at top of iter t, counted
// s_waitcnt vmcnt(7) (never 0 in loop), per-k-half {11 ds_read -> setprio(1)
// -> 24 MFMA -> setprio(0)} phases. LDS chunk-XOR swizzle (phys = lc^(row&7))
// applied on BOTH sides: pre-swizzled global source for linear gload_lds dest,
// swizzled ds_read offsets.
__global__ __launch_bounds__(512) void k_conv(const unsigned short* __restrict__ xt,
                                              const unsigned short* __restrict__ bt,
                                              const float* __restrict__ bias,
                                              float* __restrict__ out) {
  __shared__ unsigned short As[2][16384];  // [buf][kch:256][kk:64] = 2x32KB
  __shared__ unsigned short Bs[2][12288];  // [buf][m:192][kk:64]   = 2x24KB
  const int t = threadIdx.x;
  // T1: XCD-aware bijective swizzle (504 = 8*63)
  const int bid = blockIdx.x;
  const int spt = (bid & 7) * 63 + (bid >> 3);

  // ---- staging setup: thread t -> row-in-unit sr = t>>3, chunk sc = t&7
  const int sr = t >> 3;
  const int sc = t & 7;
  const int ssw = ((sc ^ (sr & 7)) << 3);   // pre-swizzled source chunk (shorts)
  const unsigned short* wsrc = bt + (size_t)sr * KG + ssw;  // + u*73728 + kt*64
  const unsigned short* xsrc0;
  const unsigned short* xsrc1;
  const unsigned short* xsrc2;
  {
    const int m0 = spt * BN + 0 * 64 + sr;
    const int m1 = spt * BN + 1 * 64 + sr;
    const int m2 = spt * BN + 2 * 64 + sr;
    xsrc0 = xt + (size_t)(m0 + 112 * (m0 / M_PER_IMG)) * 128 + ssw;
    xsrc1 = xt + (size_t)(m1 + 112 * (m1 / M_PER_IMG)) * 128 + ssw;
    xsrc2 = xt + (size_t)(m2 + 112 * (m2 / M_PER_IMG)) * 128 + ssw;
  }
  const int wvb = (t >> 6) * 512;  // wave-uniform LDS slot within a unit (shorts)

  // stage K-tile kt into buffer b: 4 A-units + 3 B-units (7 gloads/thread)
  auto STAGE = [&](int kt, int b) {
    const int rs = kt >> 1;
    const int rdiv = rs / 3;
    const int rmod = rs - rdiv * 3;
    const int xo = (rdiv * 56 + rmod) * 128 + ((kt & 1) << 6);
    const int wo = kt << 6;
    gload16(wsrc + 0 * 73728 + wo, &As[b][0 * 4096 + wvb]);
    gload16(wsrc + 1 * 73728 + wo, &As[b][1 * 4096 + wvb]);
    gload16(wsrc + 2 * 73728 + wo, &As[b][2 * 4096 + wvb]);
    gload16(wsrc + 3 * 73728 + wo, &As[b][3 * 4096 + wvb]);
    gload16(xsrc0 + xo, &Bs[b][0 * 4096 + wvb]);
    gload16(xsrc1 + xo, &Bs[b][1 * 4096 + wvb]);
    gload16(xsrc2 + xo, &Bs[b][2 * 4096 + wvb]);
  };

  // ---- fragment read setup
  const int l = t & 63;
  const int wv = t >> 6;
  const int wm = wv >> 2;   // M half (0..1): kch rows wm*128..+127
  const int wn = wv & 3;    // N quarter: spatial cols wn*48..+47
  const int lr = l & 15;
  const int hh = l >> 4;    // 0..3
  const int chbase = ((hh ^ (lr & 7)) << 3);  // phys chunk offset, k-half 0
  int abase[8], bbase[3];
#pragma unroll
  for (int f = 0; f < 8; ++f) abase[f] = (wm * 128 + f * 16 + lr) << 6;
#pragma unroll
  for (int fn = 0; fn < 3; ++fn) bbase[fn] = (wn * 48 + fn * 16 + lr) << 6;

  f32x4 acc[8][3];
#pragma unroll
  for (int f = 0; f < 8; ++f)
#pragma unroll
    for (int fn = 0; fn < 3; ++fn)
      acc[f][fn] = (f32x4){0.f, 0.f, 0.f, 0.f};

  STAGE(0, 0);
#pragma unroll 2
  for (int kt = 0; kt < 18; ++kt) {
    const int b = kt & 1;
    STAGE(kt + 1 < 18 ? kt + 1 : 17, b ^ 1);   // tail: dummy re-stage, never read
    asm volatile("s_waitcnt vmcnt(7)" ::: "memory");  // tile kt's 7 loads landed
    __builtin_amdgcn_s_barrier();
    __builtin_amdgcn_sched_barrier(0);          // pin ds_reads below barrier
#pragma unroll
    for (int ks = 0; ks < 2; ++ks) {
      const int ch = chbase ^ (ks << 5);        // k-half flips chunk bit 2
      bf16x8 af[8], bfr[3];
#pragma unroll
      for (int f = 0; f < 8; ++f) af[f] = *(const bf16x8*)&As[b][abase[f] + ch];
#pragma unroll
      for (int fn = 0; fn < 3; ++fn) bfr[fn] = *(const bf16x8*)&Bs[b][bbase[fn] + ch];
      __builtin_amdgcn_s_setprio(1);
#pragma unroll
      for (int f = 0; f < 8; ++f)
#pragma unroll
        for (int fn = 0; fn < 3; ++fn)
          acc[f][fn] = __builtin_amdgcn_mfma_f32_16x16x32_bf16(af[f], bfr[fn], acc[f][fn], 0, 0, 0);
      __builtin_amdgcn_s_setprio(0);
    }
    __builtin_amdgcn_s_barrier();               // all reads of buf b done
  }
  asm volatile("s_waitcnt vmcnt(0)" ::: "memory");  // drain dummy stage before exit

  // ---- epilogue: D row=(hh*4+reg) -> k channel; col=lr -> spatial
  float bv[8][4];
#pragma unroll
  for (int f = 0; f < 8; ++f)
#pragma unroll
    for (int rg = 0; rg < 4; ++rg)
      bv[f][rg] = bias[wm * 128 + f * 16 + hh * 4 + rg];

#pragma unroll
  for (int fn = 0; fn < 3; ++fn) {
    const int m = spt * BN + wn * 48 + fn * 16 + lr;
    const int ni = m / M_PER_IMG;
    const int rem = m - ni * M_PER_IMG;
    const int oh = rem / OWP;
    const int ow = rem - oh * OWP;
    if (ow < 54) {
      float* op = out + (size_t)ni * (K_OUT * OUT_HW) + oh * 54 + ow;
#pragma unroll
      for (int f = 0; f < 8; ++f) {
        const int kbase = wm * 128 + f * 16 + hh * 4;
#pragma unroll
        for (int rg = 0; rg < 4; ++rg)
          op[(size_t)(kbase + rg) * OUT_HW] = acc[f][fn][rg] + bv[f][rg];
      }
    }
  }
}

extern "C" void kernel_launch(void* const* d_in, const int* in_sizes, int n_in,
                              void* d_out, int out_size, void* d_ws, size_t ws_size,
                              hipStream_t stream) {
  const float* x = (const float*)d_in[0];
  const float* w = (const float*)d_in[1];
  const float* bias = (const float*)d_in[2];
  float* out = (float*)d_out;
  unsigned char* ws = (unsigned char*)d_ws;
  unsigned* mx = (unsigned*)ws;
  unsigned short* bt = (unsigned short*)(ws + 4096);
  unsigned short* xt = (unsigned short*)(ws + 593920);

  hipMemsetAsync(mx, 0, 4, stream);
  k_absmax<<<1152, 256, 0, stream>>>(w, mx);           // 294912 / 256
  k_quant<<<1152, 256, 0, stream>>>(w, mx, bt);
  k_xt<<<32 * 49, 256, 0, stream>>>(x, xt);
  k_conv<<<NBLK, 512, 0, stream>>>(xt, bt, bias, out);
}

// Round 5
// 121.020 us; speedup vs baseline: 1.0989x; 1.0989x over previous
//
#include <hip/hip_runtime.h>

typedef __bf16 bf16x8 __attribute__((ext_vector_type(8)));
typedef float f32x4 __attribute__((ext_vector_type(4)));

#define C_IN 128
#define HW_IN 3136      // 56*56
#define K_OUT 256
#define OWP 56          // padded output width
#define M_PER_IMG 3024  // 54*56
#define KG 1152         // 128*9
#define OUT_HW 2916     // 54*54
#define BN 192
#define NBLK 504        // 96768 / 192

// ws layout (bytes):
//   [0,4)          : absmax bits (uint)
//   [4096, 593920) : Bt bf16 [256][1152], kk = (r*3+s)*128 + c
//   [593920, ...)  : xt bf16 [n][h][w][c] + tail pad  (25.69 MB)

static __device__ __forceinline__ unsigned short f2bf(float f) {
  unsigned u = __float_as_uint(f);
  u += 0x7FFFu + ((u >> 16) & 1);   // RNE
  return (unsigned short)(u >> 16);
}

static __device__ __forceinline__ void gload16(const unsigned short* g, unsigned short* l) {
  __builtin_amdgcn_global_load_lds(
      (const __attribute__((address_space(1))) unsigned int*)g,
      (__attribute__((address_space(3))) unsigned int*)l, 16, 0, 0);
}

__global__ __launch_bounds__(256) void k_absmax(const float* __restrict__ w,
                                                unsigned* __restrict__ mx) {
  __shared__ float red[256];
  const int t = threadIdx.x;
  float v = fabsf(w[blockIdx.x * 256 + t]);
  red[t] = v;
  __syncthreads();
  for (int s = 128; s > 0; s >>= 1) {
    if (t < s) red[t] = fmaxf(red[t], red[t + s]);
    __syncthreads();
  }
  if (t == 0) atomicMax(mx, __float_as_uint(red[0]));
}

__global__ __launch_bounds__(256) void k_quant(const float* __restrict__ w,
                                               const unsigned* __restrict__ mx,
                                               unsigned short* __restrict__ bt) {
  const int idx = blockIdx.x * 256 + threadIdx.x;  // < 294912
  const float thr = 0.05f * __uint_as_float(*mx);
  const int k = idx / KG;
  const int j = idx - k * KG;
  const int rs = j >> 7;
  const int c = j & 127;
  const float v = w[k * KG + c * 9 + rs];
  float q = 0.f;
  if (v > thr) q = 1.f;
  else if (v < -thr) q = -1.f;
  bt[idx] = f2bf(q);
}

// x fp32 NCHW -> xt bf16 [n][hw][c], LDS tile transpose, XOR-swizzled (c^j)
__global__ __launch_bounds__(256) void k_xt(const float* __restrict__ x,
                                            unsigned short* __restrict__ xt) {
  __shared__ unsigned short tile[8192];
  const int n = blockIdx.x / 49;
  const int hw0 = (blockIdx.x - n * 49) * 64;
  const int t = threadIdx.x;
  const int j = t & 63;
  const int ci = t >> 6;
  const float* xp = x + (size_t)n * (C_IN * HW_IN) + hw0 + j;
#pragma unroll
  for (int it = 0; it < 32; ++it) {
    const int c = it * 4 + ci;
    tile[j * 128 + (c ^ j)] = f2bf(xp[(size_t)c * HW_IN]);
  }
  __syncthreads();
  const int jj = t >> 2;
  const int q = t & 3;
  unsigned short v[32] __attribute__((aligned(16)));
#pragma unroll
  for (int i = 0; i < 32; ++i)
    v[i] = tile[jj * 128 + ((q * 32 + i) ^ jj)];
  uint4* dst = (uint4*)(xt + (size_t)(n * HW_IN + hw0 + jj) * 128 + q * 32);
#pragma unroll
  for (int u = 0; u < 4; ++u)
    dst[u] = *(const uint4*)&v[u * 8];
}

// GEMM: D[kch][m] = sum_kk Bt[kch][kk] * A[m][kk]
// 256 kch x 192 sp x BK=64, 8 waves (4M x 2N: wave = 64 kch x 96 sp).
// m201-style 4-phase/kt schedule: phase = {ds_read frags, issue gloads,
// setprio MFMA, [vmcnt(2)], s_barrier}. Granules: g0 = A(bit5==0)+X all,
// g1 = A(bit5==1); two vmcnt(2) waits per kt, never draining to 0.
__global__ __launch_bounds__(512) void k_conv(const unsigned short* __restrict__ xt,
                                              const unsigned short* __restrict__ bt,
                                              const float* __restrict__ bias,
                                              float* __restrict__ out) {
  __shared__ unsigned short As[2][16384];  // [buf][kch:256][kk:64]
  __shared__ unsigned short Xs[2][12288];  // [buf][m:192][kk:64]
  const int t = threadIdx.x;
  const int bid = blockIdx.x;
  const int spt = (bid & 7) * 63 + (bid >> 3);   // T1 (504 = 8*63 exact)

  // ---- staging: thread t -> src row, chunk sc; source pre-swizzled
  const int sr = t >> 3;               // 0..63
  const int sc = t & 7;
  const int scs = ((sc ^ (sr & 7)) << 3);
  const int ra0 = (sr & 31) + ((sr & 32) << 1);   // {0-31, 64-95}
  const unsigned short* wsA0 = bt + (size_t)ra0 * KG + scs;
  const int mx0 = spt * BN + sr;
  const int mx1 = mx0 + 64;
  const int mx2 = mx0 + 128;
  const unsigned short* xs0 = xt + (size_t)(mx0 + 112 * (mx0 / M_PER_IMG)) * 128 + scs;
  const unsigned short* xs1 = xt + (size_t)(mx1 + 112 * (mx1 / M_PER_IMG)) * 128 + scs;
  const unsigned short* xs2 = xt + (size_t)(mx2 + 112 * (mx2 / M_PER_IMG)) * 128 + scs;
  const int wv = t >> 6;
  const int Rw = (wv < 4) ? wv * 8 : wv * 8 + 32;  // wave's A-row start (units A0/A2)
  const int dA0 = Rw * 64;            // unit A0 dest base (shorts); A1 = +8192
  const int dA2 = dA0 + 2048;         // unit A2; A3 = +8192
  const int dX = wv * 512;            // X0; X1 = +4096; X2 = +8192

  // ---- fragment read setup
  const int l = t & 63;
  const int wm = wv >> 1;   // 0..3 -> kch rows wm*64..+63
  const int wn = wv & 1;    // 0..1 -> sp cols wn*96..+95
  const int lr = l & 15;
  const int hh = l >> 4;
  const int ch0 = ((hh ^ (lr & 7)) << 3);
  int ab[4], bb[6];
#pragma unroll
  for (int f = 0; f < 4; ++f) ab[f] = (wm * 64 + f * 16 + lr) << 6;
#pragma unroll
  for (int fn = 0; fn < 6; ++fn) bb[fn] = (wn * 96 + fn * 16 + lr) << 6;

  f32x4 acc[4][6];
#pragma unroll
  for (int f = 0; f < 4; ++f)
#pragma unroll
    for (int fn = 0; fn < 6; ++fn)
      acc[f][fn] = (f32x4){0.f, 0.f, 0.f, 0.f};

  auto XO = [&](int kt) {
    const int rs = kt >> 1;
    const int rd = rs / 3;
    const int rm = rs - rd * 3;
    return (rd * 56 + rm) * 128 + ((kt & 1) << 6);
  };

  // ---- prologue: stage kt0 (g0 then g1) into buf0
  {
    const int xo = XO(0);
    gload16(wsA0, &As[0][dA0]);
    gload16(wsA0 + 128 * KG, &As[0][dA0 + 8192]);
    gload16(xs0 + xo, &Xs[0][dX]);
    gload16(xs1 + xo, &Xs[0][dX + 4096]);
    gload16(xs2 + xo, &Xs[0][dX + 8192]);
    gload16(wsA0 + 32 * KG, &As[0][dA2]);
    gload16(wsA0 + 160 * KG, &As[0][dA2 + 8192]);
  }
  asm volatile("s_waitcnt vmcnt(2)" ::: "memory");   // g0 landed (g1 in flight)
  __builtin_amdgcn_s_barrier();
  __builtin_amdgcn_sched_barrier(0);

  auto body = [&](int kt, int b, int ob) __attribute__((always_inline)) {
    const int nk = (kt + 1 < 18) ? kt + 1 : 17;   // tail: dummy re-stage into ob
    const int nwo = nk << 6;
    const int nxo = XO(nk);
    bf16x8 af0, af1, af2, af3, bf0, bf1, bf2, bf3, bf4, bf5;
    // ======== p0: frags (A g0 rows, X) @ks0; issue kt+1 A-g0
    af0 = *(const bf16x8*)&As[b][ab[0] + ch0];
    af1 = *(const bf16x8*)&As[b][ab[1] + ch0];
    bf0 = *(const bf16x8*)&Xs[b][bb[0] + ch0];
    bf1 = *(const bf16x8*)&Xs[b][bb[1] + ch0];
    bf2 = *(const bf16x8*)&Xs[b][bb[2] + ch0];
    bf3 = *(const bf16x8*)&Xs[b][bb[3] + ch0];
    bf4 = *(const bf16x8*)&Xs[b][bb[4] + ch0];
    bf5 = *(const bf16x8*)&Xs[b][bb[5] + ch0];
    gload16(wsA0 + nwo, &As[ob][dA0]);
    gload16(wsA0 + 128 * KG + nwo, &As[ob][dA0 + 8192]);
    __builtin_amdgcn_sched_barrier(0);
    __builtin_amdgcn_s_setprio(1);
    acc[0][0] = __builtin_amdgcn_mfma_f32_16x16x32_bf16(af0, bf0, acc[0][0], 0, 0, 0);
    acc[0][1] = __builtin_amdgcn_mfma_f32_16x16x32_bf16(af0, bf1, acc[0][1], 0, 0, 0);
    acc[0][2] = __builtin_amdgcn_mfma_f32_16x16x32_bf16(af0, bf2, acc[0][2], 0, 0, 0);
    acc[0][3] = __builtin_amdgcn_mfma_f32_16x16x32_bf16(af0, bf3, acc[0][3], 0, 0, 0);
    acc[0][4] = __builtin_amdgcn_mfma_f32_16x16x32_bf16(af0, bf4, acc[0][4], 0, 0, 0);
    acc[0][5] = __builtin_amdgcn_mfma_f32_16x16x32_bf16(af0, bf5, acc[0][5], 0, 0, 0);
    acc[1][0] = __builtin_amdgcn_mfma_f32_16x16x32_bf16(af1, bf0, acc[1][0], 0, 0, 0);
    acc[1][1] = __builtin_amdgcn_mfma_f32_16x16x32_bf16(af1, bf1, acc[1][1], 0, 0, 0);
    acc[1][2] = __builtin_amdgcn_mfma_f32_16x16x32_bf16(af1, bf2, acc[1][2], 0, 0, 0);
    acc[1][3] = __builtin_amdgcn_mfma_f32_16x16x32_bf16(af1, bf3, acc[1][3], 0, 0, 0);
    acc[1][4] = __builtin_amdgcn_mfma_f32_16x16x32_bf16(af1, bf4, acc[1][4], 0, 0, 0);
    acc[1][5] = __builtin_amdgcn_mfma_f32_16x16x32_bf16(af1, bf5, acc[1][5], 0, 0, 0);
    __builtin_amdgcn_s_setprio(0);
    __builtin_amdgcn_sched_barrier(0);
    asm volatile("s_waitcnt vmcnt(2)" ::: "memory");  // kt.g1 landed (2 younger)
    __builtin_amdgcn_s_barrier();
    __builtin_amdgcn_sched_barrier(0);
    // ======== p1: frags (A g1 rows) @ks0; issue kt+1 X
    af2 = *(const bf16x8*)&As[b][ab[2] + ch0];
    af3 = *(const bf16x8*)&As[b][ab[3] + ch0];
    gload16(xs0 + nxo, &Xs[ob][dX]);
    gload16(xs1 + nxo, &Xs[ob][dX + 4096]);
    gload16(xs2 + nxo, &Xs[ob][dX + 8192]);
    __builtin_amdgcn_sched_barrier(0);
    __builtin_amdgcn_s_setprio(1);
    acc[2][0] = __builtin_amdgcn_mfma_f32_16x16x32_bf16(af2, bf0, acc[2][0], 0, 0, 0);
    acc[2][1] = __builtin_amdgcn_mfma_f32_16x16x32_bf16(af2, bf1, acc[2][1], 0, 0, 0);
    acc[2][2] = __builtin_amdgcn_mfma_f32_16x16x32_bf16(af2, bf2, acc[2][2], 0, 0, 0);
    acc[2][3] = __builtin_amdgcn_mfma_f32_16x16x32_bf16(af2, bf3, acc[2][3], 0, 0, 0);
    acc[2][4] = __builtin_amdgcn_mfma_f32_16x16x32_bf16(af2, bf4, acc[2][4], 0, 0, 0);
    acc[2][5] = __builtin_amdgcn_mfma_f32_16x16x32_bf16(af2, bf5, acc[2][5], 0, 0, 0);
    acc[3][0] = __builtin_amdgcn_mfma_f32_16x16x32_bf16(af3, bf0, acc[3][0], 0, 0, 0);
    acc[3][1] = __builtin_amdgcn_mfma_f32_16x16x32_bf16(af3, bf1, acc[3][1], 0, 0, 0);
    acc[3][2] = __builtin_amdgcn_mfma_f32_16x16x32_bf16(af3, bf2, acc[3][2], 0, 0, 0);
    acc[3][3] = __builtin_amdgcn_mfma_f32_16x16x32_bf16(af3, bf3, acc[3][3], 0, 0, 0);
    acc[3][4] = __builtin_amdgcn_mfma_f32_16x16x32_bf16(af3, bf4, acc[3][4], 0, 0, 0);
    acc[3][5] = __builtin_amdgcn_mfma_f32_16x16x32_bf16(af3, bf5, acc[3][5], 0, 0, 0);
    __builtin_amdgcn_s_setprio(0);
    __builtin_amdgcn_sched_barrier(0);
    __builtin_amdgcn_s_barrier();
    __builtin_amdgcn_sched_barrier(0);
    // ======== p2: frags @ks1 (A g0 rows, X); issue kt+1 A-g1
    {
      const int ch1 = ch0 ^ 32;
      af0 = *(const bf16x8*)&As[b][ab[0] + ch1];
      af1 = *(const bf16x8*)&As[b][ab[1] + ch1];
      bf0 = *(const bf16x8*)&Xs[b][bb[0] + ch1];
      bf1 = *(const bf16x8*)&Xs[b][bb[1] + ch1];
      bf2 = *(const bf16x8*)&Xs[b][bb[2] + ch1];
      bf3 = *(const bf16x8*)&Xs[b][bb[3] + ch1];
      bf4 = *(const bf16x8*)&Xs[b][bb[4] + ch1];
      bf5 = *(const bf16x8*)&Xs[b][bb[5] + ch1];
      gload16(wsA0 + 32 * KG + nwo, &As[ob][dA2]);
      gload16(wsA0 + 160 * KG + nwo, &As[ob][dA2 + 8192]);
      __builtin_amdgcn_sched_barrier(0);
      __builtin_amdgcn_s_setprio(1);
      acc[0][0] = __builtin_amdgcn_mfma_f32_16x16x32_bf16(af0, bf0, acc[0][0], 0, 0, 0);
      acc[0][1] = __builtin_amdgcn_mfma_f32_16x16x32_bf16(af0, bf1, acc[0][1], 0, 0, 0);
      acc[0][2] = __builtin_amdgcn_mfma_f32_16x16x32_bf16(af0, bf2, acc[0][2], 0, 0, 0);
      acc[0][3] = __builtin_amdgcn_mfma_f32_16x16x32_bf16(af0, bf3, acc[0][3], 0, 0, 0);
      acc[0][4] = __builtin_amdgcn_mfma_f32_16x16x32_bf16(af0, bf4, acc[0][4], 0, 0, 0);
      acc[0][5] = __builtin_amdgcn_mfma_f32_16x16x32_bf16(af0, bf5, acc[0][5], 0, 0, 0);
      acc[1][0] = __builtin_amdgcn_mfma_f32_16x16x32_bf16(af1, bf0, acc[1][0], 0, 0, 0);
      acc[1][1] = __builtin_amdgcn_mfma_f32_16x16x32_bf16(af1, bf1, acc[1][1], 0, 0, 0);
      acc[1][2] = __builtin_amdgcn_mfma_f32_16x16x32_bf16(af1, bf2, acc[1][2], 0, 0, 0);
      acc[1][3] = __builtin_amdgcn_mfma_f32_16x16x32_bf16(af1, bf3, acc[1][3], 0, 0, 0);
      acc[1][4] = __builtin_amdgcn_mfma_f32_16x16x32_bf16(af1, bf4, acc[1][4], 0, 0, 0);
      acc[1][5] = __builtin_amdgcn_mfma_f32_16x16x32_bf16(af1, bf5, acc[1][5], 0, 0, 0);
      __builtin_amdgcn_s_setprio(0);
      __builtin_amdgcn_sched_barrier(0);
      __builtin_amdgcn_s_barrier();
      __builtin_amdgcn_sched_barrier(0);
      // ======== p3: frags (A g1 rows) @ks1; no issue
      af2 = *(const bf16x8*)&As[b][ab[2] + ch1];
      af3 = *(const bf16x8*)&As[b][ab[3] + ch1];
      __builtin_amdgcn_sched_barrier(0);
      __builtin_amdgcn_s_setprio(1);
      acc[2][0] = __builtin_amdgcn_mfma_f32_16x16x32_bf16(af2, bf0, acc[2][0], 0, 0, 0);
      acc[2][1] = __builtin_amdgcn_mfma_f32_16x16x32_bf16(af2, bf1, acc[2][1], 0, 0, 0);
      acc[2][2] = __builtin_amdgcn_mfma_f32_16x16x32_bf16(af2, bf2, acc[2][2], 0, 0, 0);
      acc[2][3] = __builtin_amdgcn_mfma_f32_16x16x32_bf16(af2, bf3, acc[2][3], 0, 0, 0);
      acc[2][4] = __builtin_amdgcn_mfma_f32_16x16x32_bf16(af2, bf4, acc[2][4], 0, 0, 0);
      acc[2][5] = __builtin_amdgcn_mfma_f32_16x16x32_bf16(af2, bf5, acc[2][5], 0, 0, 0);
      acc[3][0] = __builtin_amdgcn_mfma_f32_16x16x32_bf16(af3, bf0, acc[3][0], 0, 0, 0);
      acc[3][1] = __builtin_amdgcn_mfma_f32_16x16x32_bf16(af3, bf1, acc[3][1], 0, 0, 0);
      acc[3][2] = __builtin_amdgcn_mfma_f32_16x16x32_bf16(af3, bf2, acc[3][2], 0, 0, 0);
      acc[3][3] = __builtin_amdgcn_mfma_f32_16x16x32_bf16(af3, bf3, acc[3][3], 0, 0, 0);
      acc[3][4] = __builtin_amdgcn_mfma_f32_16x16x32_bf16(af3, bf4, acc[3][4], 0, 0, 0);
      acc[3][5] = __builtin_amdgcn_mfma_f32_16x16x32_bf16(af3, bf5, acc[3][5], 0, 0, 0);
      __builtin_amdgcn_s_setprio(0);
      __builtin_amdgcn_sched_barrier(0);
      asm volatile("s_waitcnt vmcnt(2)" ::: "memory");  // (kt+1).g0 landed
      __builtin_amdgcn_s_barrier();
      __builtin_amdgcn_sched_barrier(0);
    }
  };

  for (int kp = 0; kp < 9; ++kp) {
    body(2 * kp, 0, 1);
    body(2 * kp + 1, 1, 0);
  }
  asm volatile("s_waitcnt vmcnt(0)" ::: "memory");

  // ---- epilogue: D row=(hh*4+rg) -> kch; col=lr -> spatial
  float bv[4][4];
#pragma unroll
  for (int f = 0; f < 4; ++f)
#pragma unroll
    for (int rg = 0; rg < 4; ++rg)
      bv[f][rg] = bias[wm * 64 + f * 16 + hh * 4 + rg];

#pragma unroll
  for (int fn = 0; fn < 6; ++fn) {
    const int m = spt * BN + wn * 96 + fn * 16 + lr;
    const int ni = m / M_PER_IMG;
    const int rem = m - ni * M_PER_IMG;
    const int oh = rem / OWP;
    const int ow = rem - oh * OWP;
    if (ow < 54) {
      float* op = out + (size_t)ni * (K_OUT * OUT_HW) + oh * 54 + ow;
#pragma unroll
      for (int f = 0; f < 4; ++f) {
        const int kbase = wm * 64 + f * 16 + hh * 4;
#pragma unroll
        for (int rg = 0; rg < 4; ++rg)
          op[(size_t)(kbase + rg) * OUT_HW] = acc[f][fn][rg] + bv[f][rg];
      }
    }
  }
}

extern "C" void kernel_launch(void* const* d_in, const int* in_sizes, int n_in,
                              void* d_out, int out_size, void* d_ws, size_t ws_size,
                              hipStream_t stream) {
  const float* x = (const float*)d_in[0];
  const float* w = (const float*)d_in[1];
  const float* bias = (const float*)d_in[2];
  float* out = (float*)d_out;
  unsigned char* ws = (unsigned char*)d_ws;
  unsigned* mx = (unsigned*)ws;
  unsigned short* bt = (unsigned short*)(ws + 4096);
  unsigned short* xt = (unsigned short*)(ws + 593920);

  hipMemsetAsync(mx, 0, 4, stream);
  k_absmax<<<1152, 256, 0, stream>>>(w, mx);
  k_quant<<<1152, 256, 0, stream>>>(w, mx, bt);
  k_xt<<<32 * 49, 256, 0, stream>>>(x, xt);
  k_conv<<<NBLK, 512, 0, stream>>>(xt, bt, bias, out);
}